// Round 1
// baseline (432.308 us; speedup 1.0000x reference)
//
#include <hip/hip_runtime.h>

// InversePixelShuffle (pixel_unshuffle), k=2.
// in : (B=8, C=32, H=512, W=512) fp32
// out: (B=8, C*4=128, Ho=256, Wo=256) fp32
// out[b, c*4 + y*2 + x_, h, w] = in[b, c, h*2 + y, w*2 + x_]
//
// Each work-item g handles 8 contiguous input floats (one half of a W-row
// chunk): flat input offset = g*8 (rows are contiguous in the flat array).
// Those 8 floats deinterleave into 4 floats for the even-x_ output channel
// and 4 floats for the odd-x_ output channel, both stored as float4.
// Reads: 2x float4/lane, contiguous across the wave. Writes: 2x float4/lane,
// contiguous across the wave (two separate output rows). Pure shifts/masks
// for index math (all dims are powers of two).

#define N_GROUPS (8u * 32u * 512u * 512u / 8u)  // 8,388,608 work items

__global__ __launch_bounds__(256) void ipshuf_k2_kernel(
    const float* __restrict__ in, float* __restrict__ out, unsigned n_groups) {
    unsigned idx = blockIdx.x * blockDim.x + threadIdx.x;
    unsigned stride = gridDim.x * blockDim.x;
    for (unsigned g = idx; g < n_groups; g += stride) {
        // Input: 8 contiguous floats at flat offset g*8.
        const float4* p = reinterpret_cast<const float4*>(in) + (size_t)g * 2u;
        float4 a = p[0];
        float4 b = p[1];

        // Decompose g: q = which 8-float chunk within the 512-wide row (0..63),
        // r = global row index over (b, c, h_in).
        unsigned q    = g & 63u;
        unsigned r    = g >> 6;
        unsigned h_in = r & 511u;
        unsigned bc   = r >> 9;          // b*32 + c
        unsigned y    = h_in & 1u;
        unsigned ho   = h_in >> 1;

        // Output plane index: b*128 + c*4 + y*2 + x_  ==  bc*4 + y*2 + x_.
        // Plane size = 256*256 = 65536.
        size_t out0 = ((size_t)((bc << 2) | (y << 1)) << 16) + ((size_t)ho << 8) + (q << 2);

        float4 even = make_float4(a.x, a.z, b.x, b.z);  // x_ = 0
        float4 odd  = make_float4(a.y, a.w, b.y, b.w);  // x_ = 1

        *reinterpret_cast<float4*>(out + out0)          = even;
        *reinterpret_cast<float4*>(out + out0 + 65536u) = odd;
    }
}

extern "C" void kernel_launch(void* const* d_in, const int* in_sizes, int n_in,
                              void* d_out, int out_size, void* d_ws, size_t ws_size,
                              hipStream_t stream) {
    const float* in = (const float*)d_in[0];
    float* out = (float*)d_out;
    unsigned n_groups = N_GROUPS;
    dim3 block(256);
    dim3 grid(2048);  // ~8 blocks/CU; grid-stride covers the rest
    ipshuf_k2_kernel<<<grid, block, 0, stream>>>(in, out, n_groups);
}

// Round 2
// 431.861 us; speedup vs baseline: 1.0010x; 1.0010x over previous
//
#include <hip/hip_runtime.h>

// InversePixelShuffle (pixel_unshuffle), k=2.
// in : (B=8, C=32, H=512, W=512) fp32   (268 MB)
// out: (B=8, C*4=128, Ho=256, Wo=256) fp32
// out[b, c*4 + y*2 + x_, ho, wo] = in[b, c, ho*2 + y, wo*2 + x_]
//
// Fully per-instruction-coalesced version:
//  - each lane loads ONE float4 (16 B/lane, lanes contiguous -> 1 KiB/wave/instr)
//  - deinterleave in registers: {v.x,v.z} -> even-x_ plane, {v.y,v.w} -> odd-x_ plane
//  - two float2 stores (8 B/lane, lanes contiguous -> 512 B/wave/instr each),
//    even plane at flat offset `base`, odd plane at `base + 65536` (adjacent plane)
// All index math is shifts/masks (every dim is a power of two).

#define N_VEC4 (8u * 32u * 512u * 512u / 4u)  // 16,777,216 float4 work items

__global__ __launch_bounds__(256) void ipshuf_k2_kernel(
    const float* __restrict__ in, float* __restrict__ out) {
    unsigned idx = blockIdx.x * blockDim.x + threadIdx.x;
    unsigned stride = gridDim.x * blockDim.x;
    for (unsigned g = idx; g < N_VEC4; g += stride) {
        float4 v = reinterpret_cast<const float4*>(in)[g];

        unsigned p    = g & 127u;   // which float4 within the 512-wide input row
        unsigned r    = g >> 7;     // global input row over (b, c, h_in)
        unsigned h_in = r & 511u;
        unsigned bc   = r >> 9;     // b*32 + c
        unsigned y    = h_in & 1u;
        unsigned ho   = h_in >> 1;

        // even-x_ output plane index = bc*4 + y*2 ; odd plane is +1.
        // plane size = 256*256 = 65536 floats; within-row float offset = 2*p.
        size_t base = ((size_t)((bc << 2) | (y << 1)) << 16) + (ho << 8) + (p << 1);

        float2 ev = make_float2(v.x, v.z);
        float2 od = make_float2(v.y, v.w);

        *reinterpret_cast<float2*>(out + base)          = ev;
        *reinterpret_cast<float2*>(out + base + 65536u) = od;
    }
}

extern "C" void kernel_launch(void* const* d_in, const int* in_sizes, int n_in,
                              void* d_out, int out_size, void* d_ws, size_t ws_size,
                              hipStream_t stream) {
    const float* in = (const float*)d_in[0];
    float* out = (float*)d_out;
    dim3 block(256);
    dim3 grid(2048);  // 8 blocks/CU; grid-stride (32 iters/thread) covers all work
    ipshuf_k2_kernel<<<grid, block, 0, stream>>>(in, out);
}